// Round 4
// baseline (14.329 us; speedup 1.0000x reference)
//
#include <hip/hip_runtime.h>

// SetConv via on-the-fly-A MFMA GEMM (uniform-sigma fast path).
//
// uniform sigma (runtime-detected):
//   out[b,m,o] = sum_n exp2(kcu*(x[b,n]-t[b,m])^2) * Z[b,n,o] + bias[o]
//   Z = y @ W^T precomputed (f16, B-fragment order) by setconv_zprep into d_ws.
//   Main: block = (b, 16-m tile), 512 threads = 8 waves, n split 8-way
//   (128 n per wave = 4 chunks of 32). Wave's entire zf slice (8x f16x8)
//   prefetched up-front -> main loop is pure exp/VALU/MFMA. f32 acc,
//   8-way LDS cross-wave reduce, bias epilogue (512 outputs = 512 threads).
//
// non-uniform sigma: correct VALU fallback (never taken for this input).
//
// Fragment layouts (gfx950 16x16x32, verified round 3, absmax 0.125):
//   A: lane l -> row m = l&15, k = 4*(l>>4) + (j&3) + 16*(j>>2), j=0..7
//   B: lane l -> col o = l&15, k same mapping
//   D: lane l -> col o = l&15, row m = 4*(l>>4) + reg

#define B_SZ 8
#define N_SZ 1024
#define M_SZ 1024
#define C_SZ 16
#define O_SZ 32
#define LOG2E 1.4426950408889634f

typedef _Float16 f16x8 __attribute__((ext_vector_type(8)));
typedef float    f32x4 __attribute__((ext_vector_type(4)));

// ---------------- kernel 1: Z = y @ W^T, packed in B-fragment order ----------------
// grid: (b, kc) = 8*32 = 256 blocks, 256 threads.
// zf element index: ((b*32+kc)*2 + h)*512 + l*8 + j   (f16)
__global__ __launch_bounds__(256) void setconv_zprep(
    const float* __restrict__ y, const float* __restrict__ W,
    _Float16* __restrict__ zf)
{
    const int b  = blockIdx.x >> 5;
    const int kc = blockIdx.x & 31;
    __shared__ float zt[32][33]; // [n_local][o], padded

    const int t  = threadIdx.x;
    const int nl = t >> 3;   // 0..31
    const int og = t & 7;    // o-group of 4
    const int n  = kc * 32 + nl;

    const float* yr = y + ((size_t)b * N_SZ + n) * C_SZ;
    f32x4 y0 = *(const f32x4*)(yr +  0);
    f32x4 y1 = *(const f32x4*)(yr +  4);
    f32x4 y2 = *(const f32x4*)(yr +  8);
    f32x4 y3 = *(const f32x4*)(yr + 12);

#pragma unroll
    for (int oo = 0; oo < 4; ++oo) {
        const int o = og * 4 + oo;
        const float* wr = W + o * C_SZ;
        f32x4 w0 = *(const f32x4*)(wr +  0);
        f32x4 w1 = *(const f32x4*)(wr +  4);
        f32x4 w2 = *(const f32x4*)(wr +  8);
        f32x4 w3 = *(const f32x4*)(wr + 12);
        float v = y0[0]*w0[0];
        v = fmaf(y0[1], w0[1], v); v = fmaf(y0[2], w0[2], v); v = fmaf(y0[3], w0[3], v);
        v = fmaf(y1[0], w1[0], v); v = fmaf(y1[1], w1[1], v); v = fmaf(y1[2], w1[2], v); v = fmaf(y1[3], w1[3], v);
        v = fmaf(y2[0], w2[0], v); v = fmaf(y2[1], w2[1], v); v = fmaf(y2[2], w2[2], v); v = fmaf(y2[3], w2[3], v);
        v = fmaf(y3[0], w3[0], v); v = fmaf(y3[1], w3[1], v); v = fmaf(y3[2], w3[2], v); v = fmaf(y3[3], w3[3], v);
        zt[nl][o] = v;
    }
    __syncthreads();

    if (t < 128) {
        const int h  = t >> 6;   // o half
        const int l  = t & 63;   // lane position in fragment
        const int g  = l >> 4;
        const int oc = l & 15;
        f16x8 v;
#pragma unroll
        for (int j = 0; j < 8; ++j) {
            const int kk = 4 * g + (j & 3) + 16 * (j >> 2);
            v[j] = (_Float16)zt[kk][h * 16 + oc];
        }
        *(f16x8*)(zf + (((size_t)(b * 32 + kc) * 2 + h) * 64 + l) * 8) = v;
    }
}

// ---------------- kernel 2: main ----------------
// grid: (b, mg) = 8*64 = 512 blocks, 512 threads (8 waves, n-split 8-way).
__global__ __launch_bounds__(512, 4) void setconv_main(
    const float* __restrict__ x, const float* __restrict__ y,
    const float* __restrict__ t, const float* __restrict__ sigma,
    const float* __restrict__ W, const float* __restrict__ bias,
    const _Float16* __restrict__ zf, float* __restrict__ out)
{
    const int tid  = threadIdx.x;
    const int w    = tid >> 6;   // wave 0..7 = n-eighth
    const int lane = tid & 63;
    const int b    = blockIdx.x >> 6;
    const int mg   = blockIdx.x & 63;

    __shared__ float xs[N_SZ];
    __shared__ float red[8][2][16][16]; // [wave][o-half][m][oc], 16 KB

    f32x4 s0 = *(const f32x4*)(sigma + 0);
    f32x4 s1 = *(const f32x4*)(sigma + 4);
    f32x4 s2 = *(const f32x4*)(sigma + 8);
    f32x4 s3 = *(const f32x4*)(sigma + 12);
    const bool uni =
        (s0[0]==s0[1]) && (s0[0]==s0[2]) && (s0[0]==s0[3]) &&
        (s0[0]==s1[0]) && (s0[0]==s1[1]) && (s0[0]==s1[2]) && (s0[0]==s1[3]) &&
        (s0[0]==s2[0]) && (s0[0]==s2[1]) && (s0[0]==s2[2]) && (s0[0]==s2[3]) &&
        (s0[0]==s3[0]) && (s0[0]==s3[1]) && (s0[0]==s3[2]) && (s0[0]==s3[3]);

    if (uni) {
        // ---- prefetch this wave's entire zf slice (4 chunks x 2 halves) ----
        const _Float16* zp = zf + (size_t)(b * 32 + w * 4) * 1024 + lane * 8;
        f16x8 z0h0 = *(const f16x8*)(zp + 0 * 1024);
        f16x8 z0h1 = *(const f16x8*)(zp + 0 * 1024 + 512);
        f16x8 z1h0 = *(const f16x8*)(zp + 1 * 1024);
        f16x8 z1h1 = *(const f16x8*)(zp + 1 * 1024 + 512);
        f16x8 z2h0 = *(const f16x8*)(zp + 2 * 1024);
        f16x8 z2h1 = *(const f16x8*)(zp + 2 * 1024 + 512);
        f16x8 z3h0 = *(const f16x8*)(zp + 3 * 1024);
        f16x8 z3h1 = *(const f16x8*)(zp + 3 * 1024 + 512);

        const float kcu = -0.5f * LOG2E * __builtin_amdgcn_exp2f(-2.0f * LOG2E * s0[0]);
        // stage x[b] (4 KB)
        if (tid < 256)
            *(f32x4*)(xs + tid * 4) = *(const f32x4*)(x + b * N_SZ + tid * 4);
        const float tm = t[b * M_SZ + mg * 16 + (lane & 15)];
        __syncthreads();

        const int g = lane >> 4;
        const float* xq = xs + w * 128;

        f32x4 acc0 = {0.f, 0.f, 0.f, 0.f};
        f32x4 acc1 = {0.f, 0.f, 0.f, 0.f};

#pragma unroll
        for (int kc = 0; kc < 4; ++kc) {
            const float* xc0 = xq + kc * 32 + 4 * g;
            f32x4 xa = *(const f32x4*)(xc0);      // k = 4g+0..3
            f32x4 xb = *(const f32x4*)(xc0 + 16); // k = 16+4g+0..3
            f16x8 af;
#pragma unroll
            for (int j = 0; j < 4; ++j) {
                const float d = xa[j] - tm;
                af[j] = (_Float16)__builtin_amdgcn_exp2f(kcu * d * d);
            }
#pragma unroll
            for (int j = 0; j < 4; ++j) {
                const float d = xb[j] - tm;
                af[4 + j] = (_Float16)__builtin_amdgcn_exp2f(kcu * d * d);
            }
            const f16x8 bz0 = (kc == 0) ? z0h0 : (kc == 1) ? z1h0 : (kc == 2) ? z2h0 : z3h0;
            const f16x8 bz1 = (kc == 0) ? z0h1 : (kc == 1) ? z1h1 : (kc == 2) ? z2h1 : z3h1;
            acc0 = __builtin_amdgcn_mfma_f32_16x16x32_f16(af, bz0, acc0, 0, 0, 0);
            acc1 = __builtin_amdgcn_mfma_f32_16x16x32_f16(af, bz1, acc1, 0, 0, 0);
        }

#pragma unroll
        for (int r = 0; r < 4; ++r) {
            red[w][0][g * 4 + r][lane & 15] = acc0[r];
            red[w][1][g * 4 + r][lane & 15] = acc1[r];
        }
        __syncthreads();

        // 512 threads -> 512 outputs (16 m x 32 o)
        {
            const int mi = tid >> 5, o = tid & 31;
            const int h = o >> 4, oc = o & 15;
            float v = bias[o];
#pragma unroll
            for (int wv = 0; wv < 8; ++wv) v += red[wv][h][mi][oc];
            out[((size_t)(b * M_SZ + mg * 16 + mi)) * O_SZ + o] = v;
        }
    } else {
        // -------- fallback: arbitrary per-channel sigma (VALU path) --------
        const int j  = lane >> 2;  // 16 n per iter
        const int cg = lane & 3;   // 4 channels
        f32x4 slv = *(const f32x4*)(sigma + cg * 4);
        f32x4 kl;
#pragma unroll
        for (int c = 0; c < 4; ++c)
            kl[c] = -0.5f * LOG2E * __builtin_amdgcn_exp2f(-2.0f * LOG2E * slv[c]);

        // wave w owns m = mg*16 + w*2 + {0,1}
        const float tv0 = t[b * M_SZ + mg * 16 + w * 2 + 0];
        const float tv1 = t[b * M_SZ + mg * 16 + w * 2 + 1];

        f32x4 acc0 = {0.f, 0.f, 0.f, 0.f};
        f32x4 acc1 = {0.f, 0.f, 0.f, 0.f};

        for (int it = 0; it < 64; ++it) {
            const int n = it * 16 + j;
            const float xc = x[b * N_SZ + n];
            const f32x4 yc = *(const f32x4*)(y + ((size_t)b * N_SZ + n) * C_SZ + cg * 4);
            const float d0 = xc - tv0, d1 = xc - tv1;
            const float q0 = d0 * d0,  q1 = d1 * d1;
#pragma unroll
            for (int c = 0; c < 4; ++c) {
                acc0[c] = fmaf(__builtin_amdgcn_exp2f(q0 * kl[c]), yc[c], acc0[c]);
                acc1[c] = fmaf(__builtin_amdgcn_exp2f(q1 * kl[c]), yc[c], acc1[c]);
            }
        }
#pragma unroll
        for (int mask = 4; mask <= 32; mask <<= 1) {
#pragma unroll
            for (int c = 0; c < 4; ++c) {
                acc0[c] += __shfl_xor(acc0[c], mask);
                acc1[c] += __shfl_xor(acc1[c], mask);
            }
        }
        float* rp = &red[0][0][0][0]; // reuse as [16 m][16 c]
        if (lane < 4) {
            *(f32x4*)(rp + (w * 2 + 0) * 16 + lane * 4) = acc0;
            *(f32x4*)(rp + (w * 2 + 1) * 16 + lane * 4) = acc1;
        }
        __syncthreads();
        {
            const int mi = tid >> 5, o = tid & 31;
            const float* wr = W + o * C_SZ;
            float v = bias[o];
#pragma unroll
            for (int c = 0; c < C_SZ; ++c) v = fmaf(rp[mi * 16 + c], wr[c], v);
            out[((size_t)(b * M_SZ + mg * 16 + mi)) * O_SZ + o] = v;
        }
    }
}

extern "C" void kernel_launch(void* const* d_in, const int* in_sizes, int n_in,
                              void* d_out, int out_size, void* d_ws, size_t ws_size,
                              hipStream_t stream) {
    const float* x     = (const float*)d_in[0];
    const float* y     = (const float*)d_in[1];
    const float* t     = (const float*)d_in[2];
    const float* sigma = (const float*)d_in[3];
    const float* W     = (const float*)d_in[4];
    const float* bias  = (const float*)d_in[5];
    float* out = (float*)d_out;
    _Float16* zf = (_Float16*)d_ws; // 8*32*2*512 f16 = 512 KB

    setconv_zprep<<<B_SZ * 32, 256, 0, stream>>>(y, W, zf);
    setconv_main<<<B_SZ * 64, 512, 0, stream>>>(x, y, t, sigma, W, bias, zf, out);
}

// Round 5
// 9.716 us; speedup vs baseline: 1.4749x; 1.4749x over previous
//
#include <hip/hip_runtime.h>

// SetConv, single fused kernel (uniform-sigma MFMA fast path).
//
// uniform sigma (runtime-detected; holds for this input):
//   G[b,m,c] = sum_n exp2(kcu*(x[b,n]-t[b,m])^2) * y[b,n,c]
//   out[b,m,o] = sum_c G[b,m,c]*W[o,c] + bias[o]
//   kcu = -0.5*log2e/exp(sigma)^2.
//
// Grid: (b, mg) = 8*64 = 512 blocks x 512 threads (8 waves). Block owns a
// 16-m tile; waves split n 8-way (128 n/wave = 4 chunks of 32).
// Per chunk each wave: A-fragment = 16m x 32n exp weights generated in
// registers (8 exp2/lane), B-fragment = y[n:n+32, 0:16] read straight from
// global in fragment order (lane l -> col c=l&15; 16 lanes/64B line), one
// mfma_f32_16x16x32_f16 accumulating G (f32). LDS 8-way wave reduce, then
// 16->32 linear epilogue + bias.
//
// non-uniform sigma: correct VALU fallback (round-2 algorithm).
//
// Fragment layouts (gfx950 16x16x32, verified round 3, absmax 0.125):
//   A: lane l -> row m = l&15, k = 4*(l>>4) + (j&3) + 16*(j>>2), j=0..7
//   B: lane l -> col c = l&15, k same mapping
//   D: lane l -> col c = l&15, row m = 4*(l>>4) + reg

#define B_SZ 8
#define N_SZ 1024
#define M_SZ 1024
#define C_SZ 16
#define O_SZ 32
#define LOG2E 1.4426950408889634f

typedef _Float16 f16x8 __attribute__((ext_vector_type(8)));
typedef float    f32x4 __attribute__((ext_vector_type(4)));

__global__ __launch_bounds__(512, 4) void setconv_fused(
    const float* __restrict__ x,     // (B, N)
    const float* __restrict__ y,     // (B, N, C)
    const float* __restrict__ t,     // (B, M)
    const float* __restrict__ sigma, // (C)
    const float* __restrict__ W,     // (O, C)
    const float* __restrict__ bias,  // (O)
    float* __restrict__ out)         // (B, M, O)
{
    const int tid  = threadIdx.x;
    const int w    = tid >> 6;   // wave 0..7 = n-eighth
    const int lane = tid & 63;
    const int b    = blockIdx.x >> 6;
    const int mg   = blockIdx.x & 63;

    __shared__ float xs[N_SZ];          // 4 KB
    __shared__ float red[8][16][16];    // 8 KB: [wave][m][c]

    f32x4 s0 = *(const f32x4*)(sigma + 0);
    f32x4 s1 = *(const f32x4*)(sigma + 4);
    f32x4 s2 = *(const f32x4*)(sigma + 8);
    f32x4 s3 = *(const f32x4*)(sigma + 12);
    const bool uni =
        (s0[0]==s0[1]) && (s0[0]==s0[2]) && (s0[0]==s0[3]) &&
        (s0[0]==s1[0]) && (s0[0]==s1[1]) && (s0[0]==s1[2]) && (s0[0]==s1[3]) &&
        (s0[0]==s2[0]) && (s0[0]==s2[1]) && (s0[0]==s2[2]) && (s0[0]==s2[3]) &&
        (s0[0]==s3[0]) && (s0[0]==s3[1]) && (s0[0]==s3[2]) && (s0[0]==s3[3]);

    if (uni) {
        const int g  = lane >> 4;
        const int g4 = 4 * g;
        const int c  = lane & 15;

        // ---- B fragments: y slice straight from global, fragment order ----
        // lane l, chunk kc, j: y[b][w*128 + kc*32 + kk(j)][c],
        // kk(j) = g4 + (j&3) + 16*(j>>2)
        const float* ybc = y + ((size_t)b * N_SZ + w * 128) * C_SZ + c;
        f16x8 bf[4];
#pragma unroll
        for (int kc = 0; kc < 4; ++kc) {
#pragma unroll
            for (int jj = 0; jj < 4; ++jj) {
                bf[kc][jj]     = (_Float16)ybc[(kc * 32 + g4 + jj) * C_SZ];
                bf[kc][4 + jj] = (_Float16)ybc[(kc * 32 + 16 + g4 + jj) * C_SZ];
            }
        }

        const float kcu = -0.5f * LOG2E * __builtin_amdgcn_exp2f(-2.0f * LOG2E * s0[0]);
        // stage x[b] (4 KB)
        if (tid < 256)
            *(f32x4*)(xs + tid * 4) = *(const f32x4*)(x + b * N_SZ + tid * 4);
        const float tm = t[b * M_SZ + mg * 16 + c];
        __syncthreads();

        const float* xq = xs + w * 128;
        f32x4 acc = {0.f, 0.f, 0.f, 0.f};

#pragma unroll
        for (int kc = 0; kc < 4; ++kc) {
            const float* xc0 = xq + kc * 32 + g4;
            f32x4 xa = *(const f32x4*)(xc0);      // k = g4+0..3
            f32x4 xb = *(const f32x4*)(xc0 + 16); // k = 16+g4+0..3
            f16x8 af;
#pragma unroll
            for (int j = 0; j < 4; ++j) {
                const float d = xa[j] - tm;
                af[j] = (_Float16)__builtin_amdgcn_exp2f(kcu * d * d);
            }
#pragma unroll
            for (int j = 0; j < 4; ++j) {
                const float d = xb[j] - tm;
                af[4 + j] = (_Float16)__builtin_amdgcn_exp2f(kcu * d * d);
            }
            acc = __builtin_amdgcn_mfma_f32_16x16x32_f16(af, bf[kc], acc, 0, 0, 0);
        }

        // D: lane -> col c = lane&15, row m = g*4 + r
#pragma unroll
        for (int r = 0; r < 4; ++r)
            red[w][g * 4 + r][c] = acc[r];
        __syncthreads();

        // ---- step 1: reduce over waves (256 threads: (mi, c)) ----
        if (tid < 256) {
            const int mi = tid >> 4, cc = tid & 15;
            float s = red[0][mi][cc];
#pragma unroll
            for (int wv = 1; wv < 8; ++wv) s += red[wv][mi][cc];
            red[0][mi][cc] = s;   // own slot, no cross-thread hazard
        }
        __syncthreads();

        // ---- step 2: 16->32 linear, 512 threads = 512 outputs ----
        {
            const int mi = tid >> 5, o = tid & 31;
            const float* gr = &red[0][mi][0];
            const float* wr = W + o * C_SZ;
            float v = bias[o];
#pragma unroll
            for (int cc = 0; cc < C_SZ; ++cc) v = fmaf(gr[cc], wr[cc], v);
            out[((size_t)(b * M_SZ + mg * 16 + mi)) * O_SZ + o] = v;
        }
    } else {
        // -------- fallback: arbitrary per-channel sigma (VALU path) --------
        const int j  = lane >> 2;  // 16 n per iter
        const int cg = lane & 3;   // 4 channels
        f32x4 slv = *(const f32x4*)(sigma + cg * 4);
        f32x4 kl;
#pragma unroll
        for (int cc = 0; cc < 4; ++cc)
            kl[cc] = -0.5f * LOG2E * __builtin_amdgcn_exp2f(-2.0f * LOG2E * slv[cc]);

        // wave w owns m = mg*16 + w*2 + {0,1}
        const float tv0 = t[b * M_SZ + mg * 16 + w * 2 + 0];
        const float tv1 = t[b * M_SZ + mg * 16 + w * 2 + 1];

        f32x4 acc0 = {0.f, 0.f, 0.f, 0.f};
        f32x4 acc1 = {0.f, 0.f, 0.f, 0.f};

        for (int it = 0; it < 64; ++it) {
            const int n = it * 16 + j;
            const float xc = x[b * N_SZ + n];
            const f32x4 yc = *(const f32x4*)(y + ((size_t)b * N_SZ + n) * C_SZ + cg * 4);
            const float d0 = xc - tv0, d1 = xc - tv1;
            const float q0 = d0 * d0,  q1 = d1 * d1;
#pragma unroll
            for (int cc = 0; cc < 4; ++cc) {
                acc0[cc] = fmaf(__builtin_amdgcn_exp2f(q0 * kl[cc]), yc[cc], acc0[cc]);
                acc1[cc] = fmaf(__builtin_amdgcn_exp2f(q1 * kl[cc]), yc[cc], acc1[cc]);
            }
        }
#pragma unroll
        for (int mask = 4; mask <= 32; mask <<= 1) {
#pragma unroll
            for (int cc = 0; cc < 4; ++cc) {
                acc0[cc] += __shfl_xor(acc0[cc], mask);
                acc1[cc] += __shfl_xor(acc1[cc], mask);
            }
        }
        float* rp = &red[0][0][0]; // reuse as [16 m][16 c]
        if (lane < 4) {
            *(f32x4*)(rp + (w * 2 + 0) * 16 + lane * 4) = acc0;
            *(f32x4*)(rp + (w * 2 + 1) * 16 + lane * 4) = acc1;
        }
        __syncthreads();
        {
            const int mi = tid >> 5, o = tid & 31;
            const float* wr = W + o * C_SZ;
            float v = bias[o];
#pragma unroll
            for (int cc = 0; cc < C_SZ; ++cc) v = fmaf(rp[mi * 16 + cc], wr[cc], v);
            out[((size_t)(b * M_SZ + mg * 16 + mi)) * O_SZ + o] = v;
        }
    }
}

extern "C" void kernel_launch(void* const* d_in, const int* in_sizes, int n_in,
                              void* d_out, int out_size, void* d_ws, size_t ws_size,
                              hipStream_t stream) {
    const float* x     = (const float*)d_in[0];
    const float* y     = (const float*)d_in[1];
    const float* t     = (const float*)d_in[2];
    const float* sigma = (const float*)d_in[3];
    const float* W     = (const float*)d_in[4];
    const float* bias  = (const float*)d_in[5];
    float* out = (float*)d_out;

    setconv_fused<<<B_SZ * 64, 512, 0, stream>>>(x, y, t, sigma, W, bias, out);
}

// Round 6
// 9.598 us; speedup vs baseline: 1.4929x; 1.0122x over previous
//
#include <hip/hip_runtime.h>

// SetConv, single fused kernel (uniform-sigma MFMA fast path).
//
//   G[b,m,c] = sum_n exp2(kcu*(x[b,n]-t[b,m])^2) * y[b,n,c]
//   out[b,m,o] = sum_c G[b,m,c]*W[o,c] + bias[o],  kcu = -0.5*log2e/exp(sigma)^2
//
// Grid: (b, mg) = 8*64 = 512 blocks x 512 threads (8 waves). Block owns a
// 16-m tile; waves split n 8-way (128 n/wave = 4 chunks of 32).
// ALL global loads (y-fragments, x, t, sigma) are issued unconditionally at
// kernel entry so their latencies overlap; uni-check/cvt/x-staging execute
// in the load shadow. Per chunk: A-fragment = 16m x 32n exp weights in
// registers (8 exp2/lane), B = y slice in fragment order (loaded at entry),
// one mfma_f32_16x16x32_f16 accumulating G (f32). LDS 8-way wave reduce,
// 16->32 linear epilogue + bias.
//
// non-uniform sigma: correct VALU fallback (never taken for this input).
//
// Fragment layouts (gfx950 16x16x32, verified round 3, absmax 0.125):
//   A: lane l -> row m = l&15, k = 4*(l>>4) + (j&3) + 16*(j>>2), j=0..7
//   B: lane l -> col c = l&15, k same mapping
//   D: lane l -> col c = l&15, row m = 4*(l>>4) + reg

#define B_SZ 8
#define N_SZ 1024
#define M_SZ 1024
#define C_SZ 16
#define O_SZ 32
#define LOG2E 1.4426950408889634f

typedef _Float16 f16x8 __attribute__((ext_vector_type(8)));
typedef float    f32x4 __attribute__((ext_vector_type(4)));
typedef float    f32x2 __attribute__((ext_vector_type(2)));

__global__ __launch_bounds__(512, 4) void setconv_fused(
    const float* __restrict__ x,     // (B, N)
    const float* __restrict__ y,     // (B, N, C)
    const float* __restrict__ t,     // (B, M)
    const float* __restrict__ sigma, // (C)
    const float* __restrict__ W,     // (O, C)
    const float* __restrict__ bias,  // (O)
    float* __restrict__ out)         // (B, M, O)
{
    const int tid  = threadIdx.x;
    const int w    = tid >> 6;   // wave 0..7 = n-eighth
    const int lane = tid & 63;
    const int b    = blockIdx.x >> 6;
    const int mg   = blockIdx.x & 63;

    const int g  = lane >> 4;
    const int g4 = 4 * g;
    const int c  = lane & 15;

    __shared__ float xs[N_SZ];          // 4 KB
    __shared__ float red[8][16][16];    // 8 KB: [wave][m][c]

    // ================= hoisted, unconditional global loads =================
    // (1) y B-fragments in fragment order: lane l -> col c, rows per quarter
    const float* ybc = y + ((size_t)b * N_SZ + w * 128) * C_SZ + c;
    float yraw[32];
#pragma unroll
    for (int kc = 0; kc < 4; ++kc) {
#pragma unroll
        for (int jj = 0; jj < 4; ++jj) {
            yraw[kc * 8 + jj]     = ybc[(kc * 32 + g4 + jj) * C_SZ];
            yraw[kc * 8 + 4 + jj] = ybc[(kc * 32 + 16 + g4 + jj) * C_SZ];
        }
    }
    // (2) x -> LDS (512 threads x 2 floats = 1024)
    const f32x2 xv = *(const f32x2*)(x + b * N_SZ + tid * 2);
    // (3) t value for this lane's m-column
    const float tm = t[b * M_SZ + mg * 16 + c];
    // (4) sigma
    f32x4 s0 = *(const f32x4*)(sigma + 0);
    f32x4 s1 = *(const f32x4*)(sigma + 4);
    f32x4 s2 = *(const f32x4*)(sigma + 8);
    f32x4 s3 = *(const f32x4*)(sigma + 12);

    // work in the load shadow: uni check + f16 conversion + x staging
    const bool uni =
        (s0[0]==s0[1]) && (s0[0]==s0[2]) && (s0[0]==s0[3]) &&
        (s0[0]==s1[0]) && (s0[0]==s1[1]) && (s0[0]==s1[2]) && (s0[0]==s1[3]) &&
        (s0[0]==s2[0]) && (s0[0]==s2[1]) && (s0[0]==s2[2]) && (s0[0]==s2[3]) &&
        (s0[0]==s3[0]) && (s0[0]==s3[1]) && (s0[0]==s3[2]) && (s0[0]==s3[3]);

    f16x8 bf[4];
#pragma unroll
    for (int kc = 0; kc < 4; ++kc)
#pragma unroll
        for (int j = 0; j < 8; ++j)
            bf[kc][j] = (_Float16)yraw[kc * 8 + j];

    *(f32x2*)(xs + tid * 2) = xv;
    __syncthreads();

    if (uni) {
        const float kcu = -0.5f * LOG2E * __builtin_amdgcn_exp2f(-2.0f * LOG2E * s0[0]);
        const float* xq = xs + w * 128;
        f32x4 acc = {0.f, 0.f, 0.f, 0.f};

#pragma unroll
        for (int kc = 0; kc < 4; ++kc) {
            const float* xc0 = xq + kc * 32 + g4;
            f32x4 xa = *(const f32x4*)(xc0);      // k = g4+0..3
            f32x4 xb = *(const f32x4*)(xc0 + 16); // k = 16+g4+0..3
            f16x8 af;
#pragma unroll
            for (int j = 0; j < 4; ++j) {
                const float d = xa[j] - tm;
                af[j] = (_Float16)__builtin_amdgcn_exp2f(kcu * d * d);
            }
#pragma unroll
            for (int j = 0; j < 4; ++j) {
                const float d = xb[j] - tm;
                af[4 + j] = (_Float16)__builtin_amdgcn_exp2f(kcu * d * d);
            }
            acc = __builtin_amdgcn_mfma_f32_16x16x32_f16(af, bf[kc], acc, 0, 0, 0);
        }

        // D: lane -> col c = lane&15, row m = g*4 + r
#pragma unroll
        for (int r = 0; r < 4; ++r)
            red[w][g * 4 + r][c] = acc[r];
        __syncthreads();

        // step 1: reduce over waves (256 threads: (mi, c))
        if (tid < 256) {
            const int mi = tid >> 4, cc = tid & 15;
            float s = red[0][mi][cc];
#pragma unroll
            for (int wv = 1; wv < 8; ++wv) s += red[wv][mi][cc];
            red[0][mi][cc] = s;   // own slot, no cross-thread hazard
        }
        __syncthreads();

        // step 2: 16->32 linear, 512 threads = 512 outputs
        {
            const int mi = tid >> 5, o = tid & 31;
            const float* gr = &red[0][mi][0];
            const float* wr = W + o * C_SZ;
            float v = bias[o];
#pragma unroll
            for (int cc = 0; cc < C_SZ; ++cc) v = fmaf(gr[cc], wr[cc], v);
            out[((size_t)(b * M_SZ + mg * 16 + mi)) * O_SZ + o] = v;
        }
    } else {
        // -------- fallback: arbitrary per-channel sigma (VALU path) --------
        const int j  = lane >> 2;  // 16 n per iter
        const int cg = lane & 3;   // 4 channels
        f32x4 slv = *(const f32x4*)(sigma + cg * 4);
        f32x4 kl;
#pragma unroll
        for (int cc = 0; cc < 4; ++cc)
            kl[cc] = -0.5f * LOG2E * __builtin_amdgcn_exp2f(-2.0f * LOG2E * slv[cc]);

        // wave w owns m = mg*16 + w*2 + {0,1}
        const float tv0 = t[b * M_SZ + mg * 16 + w * 2 + 0];
        const float tv1 = t[b * M_SZ + mg * 16 + w * 2 + 1];

        f32x4 acc0 = {0.f, 0.f, 0.f, 0.f};
        f32x4 acc1 = {0.f, 0.f, 0.f, 0.f};

        for (int it = 0; it < 64; ++it) {
            const int n = it * 16 + j;
            const float xc = xs[n];
            const f32x4 yc = *(const f32x4*)(y + ((size_t)b * N_SZ + n) * C_SZ + cg * 4);
            const float d0 = xc - tv0, d1 = xc - tv1;
            const float q0 = d0 * d0,  q1 = d1 * d1;
#pragma unroll
            for (int cc = 0; cc < 4; ++cc) {
                acc0[cc] = fmaf(__builtin_amdgcn_exp2f(q0 * kl[cc]), yc[cc], acc0[cc]);
                acc1[cc] = fmaf(__builtin_amdgcn_exp2f(q1 * kl[cc]), yc[cc], acc1[cc]);
            }
        }
#pragma unroll
        for (int mask = 4; mask <= 32; mask <<= 1) {
#pragma unroll
            for (int cc = 0; cc < 4; ++cc) {
                acc0[cc] += __shfl_xor(acc0[cc], mask);
                acc1[cc] += __shfl_xor(acc1[cc], mask);
            }
        }
        float* rp = &red[0][0][0]; // reuse as [16 m][16 c]
        if (lane < 4) {
            *(f32x4*)(rp + (w * 2 + 0) * 16 + lane * 4) = acc0;
            *(f32x4*)(rp + (w * 2 + 1) * 16 + lane * 4) = acc1;
        }
        __syncthreads();
        {
            const int mi = tid >> 5, o = tid & 31;
            const float* wr = W + o * C_SZ;
            float v = bias[o];
#pragma unroll
            for (int cc = 0; cc < C_SZ; ++cc) v = fmaf(rp[mi * 16 + cc], wr[cc], v);
            out[((size_t)(b * M_SZ + mg * 16 + mi)) * O_SZ + o] = v;
        }
    }
}

extern "C" void kernel_launch(void* const* d_in, const int* in_sizes, int n_in,
                              void* d_out, int out_size, void* d_ws, size_t ws_size,
                              hipStream_t stream) {
    const float* x     = (const float*)d_in[0];
    const float* y     = (const float*)d_in[1];
    const float* t     = (const float*)d_in[2];
    const float* sigma = (const float*)d_in[3];
    const float* W     = (const float*)d_in[4];
    const float* bias  = (const float*)d_in[5];
    float* out = (float*)d_out;

    setconv_fused<<<B_SZ * 64, 512, 0, stream>>>(x, y, t, sigma, W, bias, out);
}